// Round 1
// baseline (81.057 us; speedup 1.0000x reference)
//
#include <hip/hip_runtime.h>

#define BB 64
#define CC 256
#define HW 3136            // 56*56
#define VEC (HW / 4)       // 784 float4 per (b,c) plane
#define NROW (BB * CC)     // 16384

// ---------------- Kernel 1: copy x -> out, per-(b,c) sum & sumsq ----------------
__global__ __launch_bounds__(256) void reduce_copy_kernel(
    const float* __restrict__ x, float* __restrict__ out,
    float* __restrict__ s_ws, float* __restrict__ ss_ws) {
  const int r = blockIdx.x;                 // r = b*C + c
  const size_t base = (size_t)r * HW;
  const float4* __restrict__ xv = (const float4*)(x + base);
  float4* __restrict__ ov = (float4*)(out + base);

  float s = 0.f, ss = 0.f;
  for (int k = threadIdx.x; k < VEC; k += 256) {
    float4 v = xv[k];
    ov[k] = v;
    s += v.x + v.y + v.z + v.w;
    ss += v.x * v.x + v.y * v.y + v.z * v.z + v.w * v.w;
  }

  // wave(64) butterfly-free down-reduce
  for (int off = 32; off; off >>= 1) {
    s += __shfl_down(s, off, 64);
    ss += __shfl_down(ss, off, 64);
  }
  __shared__ float ls[4], lss[4];
  const int lane = threadIdx.x & 63, wid = threadIdx.x >> 6;
  if (lane == 0) { ls[wid] = s; lss[wid] = ss; }
  __syncthreads();
  if (threadIdx.x == 0) {
    s_ws[r]  = ls[0] + ls[1] + ls[2] + ls[3];
    ss_ws[r] = lss[0] + lss[1] + lss[2] + lss[3];
  }
}

// ---------------- Kernel 2: BN stats + hierarchical group stats ----------------
__global__ __launch_bounds__(256) void stats_kernel(
    const float* __restrict__ s_ws, const float* __restrict__ ss_ws,
    float* __restrict__ out) {
  const size_t OX = (size_t)NROW * HW;      // x copy size
  float* mean_bn = out + OX;                // [C]
  float* var_bn  = mean_bn + CC;            // [C]
  float* m2  = var_bn + CC;                 // [B, C/2]
  float* v2  = m2 + BB * (CC / 2);
  float* m4  = v2 + BB * (CC / 2);          // [B, C/4]
  float* v4  = m4 + BB * (CC / 4);
  float* m8  = v4 + BB * (CC / 4);          // [B, C/8]
  float* v8  = m8 + BB * (CC / 8);
  float* m16 = v8 + BB * (CC / 8);          // [B, C/16]
  float* v16 = m16 + BB * (CC / 16);

  const int b = blockIdx.x;
  const int t = threadIdx.x;

  if (b == BB) {
    // BatchNorm stats: thread t = channel
    float S = 0.f, SS = 0.f;
    for (int bb = 0; bb < BB; ++bb) {
      S += s_ws[bb * CC + t];
      SS += ss_ws[bb * CC + t];
    }
    const float inv_n = 1.f / ((float)BB * (float)HW);
    const float m = S * inv_n;
    mean_bn[t] = m;
    var_bn[t]  = SS * inv_n - m * m;
    return;
  }

  __shared__ float ls2[128], lss2[128];
  __shared__ float ls4[64],  lss4[64];
  __shared__ float ls8[32],  lss8[32];

  if (t < 128) {
    float s2  = s_ws[b * CC + 2 * t] + s_ws[b * CC + 2 * t + 1];
    float ss2 = ss_ws[b * CC + 2 * t] + ss_ws[b * CC + 2 * t + 1];
    ls2[t] = s2; lss2[t] = ss2;
    const float inv_n = 1.f / (2.f * HW);
    const float m = s2 * inv_n;
    m2[b * 128 + t] = m;
    v2[b * 128 + t] = ss2 * inv_n - m * m;
  }
  __syncthreads();
  if (t < 64) {
    float s4  = ls2[2 * t] + ls2[2 * t + 1];
    float ss4 = lss2[2 * t] + lss2[2 * t + 1];
    ls4[t] = s4; lss4[t] = ss4;
    const float inv_n = 1.f / (4.f * HW);
    const float m = s4 * inv_n;
    m4[b * 64 + t] = m;
    v4[b * 64 + t] = ss4 * inv_n - m * m;
  }
  __syncthreads();
  if (t < 32) {
    float s8  = ls4[2 * t] + ls4[2 * t + 1];
    float ss8 = lss4[2 * t] + lss4[2 * t + 1];
    ls8[t] = s8; lss8[t] = ss8;
    const float inv_n = 1.f / (8.f * HW);
    const float m = s8 * inv_n;
    m8[b * 32 + t] = m;
    v8[b * 32 + t] = ss8 * inv_n - m * m;
  }
  __syncthreads();
  if (t < 16) {
    float s16  = ls8[2 * t] + ls8[2 * t + 1];
    float ss16 = lss8[2 * t] + lss8[2 * t + 1];
    const float inv_n = 1.f / (16.f * HW);
    const float m = s16 * inv_n;
    m16[b * 16 + t] = m;
    v16[b * 16 + t] = ss16 * inv_n - m * m;
  }
}

extern "C" void kernel_launch(void* const* d_in, const int* in_sizes, int n_in,
                              void* d_out, int out_size, void* d_ws, size_t ws_size,
                              hipStream_t stream) {
  const float* x = (const float*)d_in[0];
  float* out = (float*)d_out;
  float* s_ws = (float*)d_ws;          // [B*C]
  float* ss_ws = s_ws + NROW;          // [B*C]  (total 128 KB of d_ws)

  reduce_copy_kernel<<<NROW, 256, 0, stream>>>(x, out, s_ws, ss_ws);
  stats_kernel<<<BB + 1, 256, 0, stream>>>(s_ws, ss_ws, out);
}

// Round 3
// 79.280 us; speedup vs baseline: 1.0224x; 1.0224x over previous
//
#include <hip/hip_runtime.h>

#define BB 64
#define CC 256
#define HW 3136            // 56*56
#define VEC (HW / 4)       // 784 float4 per (b,c) plane
#define NROW (BB * CC)     // 16384

typedef float f32x4 __attribute__((ext_vector_type(4)));

// ---------------- Kernel 1: copy x -> out, per-(b,c) sum & sumsq ----------------
// One 64-lane wave per (b,c) row; 4 waves (4 rows) per block.
__global__ __launch_bounds__(256) void reduce_copy_kernel(
    const float* __restrict__ x, float* __restrict__ out,
    float* __restrict__ s_ws, float* __restrict__ ss_ws) {
  const int row  = blockIdx.x * 4 + (threadIdx.x >> 6);   // global wave id = row
  const int lane = threadIdx.x & 63;
  const size_t base = (size_t)row * HW;
  const f32x4* __restrict__ xv = (const f32x4*)(x + base);
  f32x4* __restrict__ ov = (f32x4*)(out + base);

  float s = 0.f, ss = 0.f;
#pragma unroll 4
  for (int k = lane; k < VEC; k += 64) {
    f32x4 v = __builtin_nontemporal_load(&xv[k]);
    __builtin_nontemporal_store(v, &ov[k]);
    s += v.x + v.y + v.z + v.w;
    ss += v.x * v.x + v.y * v.y + v.z * v.z + v.w * v.w;
  }

  // wave64 down-reduce (no LDS, no barrier)
  for (int off = 32; off; off >>= 1) {
    s += __shfl_down(s, off, 64);
    ss += __shfl_down(ss, off, 64);
  }
  if (lane == 0) {
    s_ws[row]  = s;
    ss_ws[row] = ss;
  }
}

// ---------------- Kernel 2: BN stats + hierarchical group stats ----------------
__global__ __launch_bounds__(256) void stats_kernel(
    const float* __restrict__ s_ws, const float* __restrict__ ss_ws,
    float* __restrict__ out) {
  const size_t OX = (size_t)NROW * HW;      // x copy size
  float* mean_bn = out + OX;                // [C]
  float* var_bn  = mean_bn + CC;            // [C]
  float* m2  = var_bn + CC;                 // [B, C/2]
  float* v2  = m2 + BB * (CC / 2);
  float* m4  = v2 + BB * (CC / 2);          // [B, C/4]
  float* v4  = m4 + BB * (CC / 4);
  float* m8  = v4 + BB * (CC / 4);          // [B, C/8]
  float* v8  = m8 + BB * (CC / 8);
  float* m16 = v8 + BB * (CC / 8);          // [B, C/16]
  float* v16 = m16 + BB * (CC / 16);

  const int b = blockIdx.x;
  const int t = threadIdx.x;

  if (b == BB) {
    // BatchNorm stats: thread t = channel
    float S = 0.f, SS = 0.f;
    for (int bb = 0; bb < BB; ++bb) {
      S += s_ws[bb * CC + t];
      SS += ss_ws[bb * CC + t];
    }
    const float inv_n = 1.f / ((float)BB * (float)HW);
    const float m = S * inv_n;
    mean_bn[t] = m;
    var_bn[t]  = SS * inv_n - m * m;
    return;
  }

  __shared__ float ls2[128], lss2[128];
  __shared__ float ls4[64],  lss4[64];
  __shared__ float ls8[32],  lss8[32];

  if (t < 128) {
    float s2  = s_ws[b * CC + 2 * t] + s_ws[b * CC + 2 * t + 1];
    float ss2 = ss_ws[b * CC + 2 * t] + ss_ws[b * CC + 2 * t + 1];
    ls2[t] = s2; lss2[t] = ss2;
    const float inv_n = 1.f / (2.f * HW);
    const float m = s2 * inv_n;
    m2[b * 128 + t] = m;
    v2[b * 128 + t] = ss2 * inv_n - m * m;
  }
  __syncthreads();
  if (t < 64) {
    float s4  = ls2[2 * t] + ls2[2 * t + 1];
    float ss4 = lss2[2 * t] + lss2[2 * t + 1];
    ls4[t] = s4; lss4[t] = ss4;
    const float inv_n = 1.f / (4.f * HW);
    const float m = s4 * inv_n;
    m4[b * 64 + t] = m;
    v4[b * 64 + t] = ss4 * inv_n - m * m;
  }
  __syncthreads();
  if (t < 32) {
    float s8  = ls4[2 * t] + ls4[2 * t + 1];
    float ss8 = lss4[2 * t] + lss4[2 * t + 1];
    ls8[t] = s8; lss8[t] = ss8;
    const float inv_n = 1.f / (8.f * HW);
    const float m = s8 * inv_n;
    m8[b * 32 + t] = m;
    v8[b * 32 + t] = ss8 * inv_n - m * m;
  }
  __syncthreads();
  if (t < 16) {
    float s16  = ls8[2 * t] + ls8[2 * t + 1];
    float ss16 = lss8[2 * t] + lss8[2 * t + 1];
    const float inv_n = 1.f / (16.f * HW);
    const float m = s16 * inv_n;
    m16[b * 16 + t] = m;
    v16[b * 16 + t] = ss16 * inv_n - m * m;
  }
}

extern "C" void kernel_launch(void* const* d_in, const int* in_sizes, int n_in,
                              void* d_out, int out_size, void* d_ws, size_t ws_size,
                              hipStream_t stream) {
  const float* x = (const float*)d_in[0];
  float* out = (float*)d_out;
  float* s_ws = (float*)d_ws;          // [B*C]
  float* ss_ws = s_ws + NROW;          // [B*C]  (total 128 KB of d_ws)

  reduce_copy_kernel<<<NROW / 4, 256, 0, stream>>>(x, out, s_ws, ss_ws);
  stats_kernel<<<BB + 1, 256, 0, stream>>>(s_ws, ss_ws, out);
}

// Round 4
// 74.894 us; speedup vs baseline: 1.0823x; 1.0586x over previous
//
#include <hip/hip_runtime.h>

#define BB 64
#define CC 256
#define HW 3136            // 56*56
#define VEC (HW / 4)       // 784 float4 per (b,c) plane = 12*64 + 16
#define NROW (BB * CC)     // 16384

typedef float f32x4 __attribute__((ext_vector_type(4)));

// ---------------- Kernel 1: copy x -> out, per-(b,c) sum & sumsq ----------------
// One 64-lane wave per (b,c) row; 4 waves (4 rows) per block.
// Constant-trip-count unrolled body: 12 NT loads in flight per lane, then
// store+accumulate; explicit 16-lane tail.
__global__ __launch_bounds__(256) void reduce_copy_kernel(
    const float* __restrict__ x, float* __restrict__ out,
    float* __restrict__ s_ws, float* __restrict__ ss_ws) {
  const int row  = blockIdx.x * 4 + (threadIdx.x >> 6);
  const int lane = threadIdx.x & 63;
  const size_t base = (size_t)row * HW;
  const f32x4* __restrict__ xv = (const f32x4*)(x + base);
  f32x4* __restrict__ ov = (f32x4*)(out + base);

  f32x4 v0, v1, v2, v3, v4, v5, v6, v7, v8, v9, v10, v11, vt;
  v0  = __builtin_nontemporal_load(&xv[lane +  0 * 64]);
  v1  = __builtin_nontemporal_load(&xv[lane +  1 * 64]);
  v2  = __builtin_nontemporal_load(&xv[lane +  2 * 64]);
  v3  = __builtin_nontemporal_load(&xv[lane +  3 * 64]);
  v4  = __builtin_nontemporal_load(&xv[lane +  4 * 64]);
  v5  = __builtin_nontemporal_load(&xv[lane +  5 * 64]);
  v6  = __builtin_nontemporal_load(&xv[lane +  6 * 64]);
  v7  = __builtin_nontemporal_load(&xv[lane +  7 * 64]);
  v8  = __builtin_nontemporal_load(&xv[lane +  8 * 64]);
  v9  = __builtin_nontemporal_load(&xv[lane +  9 * 64]);
  v10 = __builtin_nontemporal_load(&xv[lane + 10 * 64]);
  v11 = __builtin_nontemporal_load(&xv[lane + 11 * 64]);
  const bool tail = lane < 16;
  if (tail) vt = __builtin_nontemporal_load(&xv[768 + lane]);

  float s = 0.f, ss = 0.f;
#define STEP(V, IDX)                                            \
  __builtin_nontemporal_store(V, &ov[IDX]);                     \
  s += V.x + V.y + V.z + V.w;                                   \
  ss += V.x * V.x + V.y * V.y + V.z * V.z + V.w * V.w;
  STEP(v0,  lane +  0 * 64)
  STEP(v1,  lane +  1 * 64)
  STEP(v2,  lane +  2 * 64)
  STEP(v3,  lane +  3 * 64)
  STEP(v4,  lane +  4 * 64)
  STEP(v5,  lane +  5 * 64)
  STEP(v6,  lane +  6 * 64)
  STEP(v7,  lane +  7 * 64)
  STEP(v8,  lane +  8 * 64)
  STEP(v9,  lane +  9 * 64)
  STEP(v10, lane + 10 * 64)
  STEP(v11, lane + 11 * 64)
  if (tail) {
    STEP(vt, 768 + lane)
  }
#undef STEP

  // wave64 down-reduce (no LDS, no barrier)
  for (int off = 32; off; off >>= 1) {
    s += __shfl_down(s, off, 64);
    ss += __shfl_down(ss, off, 64);
  }
  if (lane == 0) {
    s_ws[row]  = s;
    ss_ws[row] = ss;
  }
}

// ---------------- Kernel 2: BN stats + hierarchical group stats ----------------
__global__ __launch_bounds__(256) void stats_kernel(
    const float* __restrict__ s_ws, const float* __restrict__ ss_ws,
    float* __restrict__ out) {
  const size_t OX = (size_t)NROW * HW;      // x copy size
  float* mean_bn = out + OX;                // [C]
  float* var_bn  = mean_bn + CC;            // [C]
  float* m2  = var_bn + CC;                 // [B, C/2]
  float* v2  = m2 + BB * (CC / 2);
  float* m4  = v2 + BB * (CC / 2);          // [B, C/4]
  float* v4  = m4 + BB * (CC / 4);
  float* m8  = v4 + BB * (CC / 4);          // [B, C/8]
  float* v8  = m8 + BB * (CC / 8);
  float* m16 = v8 + BB * (CC / 8);          // [B, C/16]
  float* v16 = m16 + BB * (CC / 16);

  const int b = blockIdx.x;
  const int t = threadIdx.x;

  if (b == BB) {
    // BatchNorm stats: thread t = channel
    float S = 0.f, SS = 0.f;
    for (int bb = 0; bb < BB; ++bb) {
      S += s_ws[bb * CC + t];
      SS += ss_ws[bb * CC + t];
    }
    const float inv_n = 1.f / ((float)BB * (float)HW);
    const float m = S * inv_n;
    mean_bn[t] = m;
    var_bn[t]  = SS * inv_n - m * m;
    return;
  }

  __shared__ float ls2[128], lss2[128];
  __shared__ float ls4[64],  lss4[64];
  __shared__ float ls8[32],  lss8[32];

  if (t < 128) {
    float s2  = s_ws[b * CC + 2 * t] + s_ws[b * CC + 2 * t + 1];
    float ss2 = ss_ws[b * CC + 2 * t] + ss_ws[b * CC + 2 * t + 1];
    ls2[t] = s2; lss2[t] = ss2;
    const float inv_n = 1.f / (2.f * HW);
    const float m = s2 * inv_n;
    m2[b * 128 + t] = m;
    v2[b * 128 + t] = ss2 * inv_n - m * m;
  }
  __syncthreads();
  if (t < 64) {
    float s4  = ls2[2 * t] + ls2[2 * t + 1];
    float ss4 = lss2[2 * t] + lss2[2 * t + 1];
    ls4[t] = s4; lss4[t] = ss4;
    const float inv_n = 1.f / (4.f * HW);
    const float m = s4 * inv_n;
    m4[b * 64 + t] = m;
    v4[b * 64 + t] = ss4 * inv_n - m * m;
  }
  __syncthreads();
  if (t < 32) {
    float s8  = ls4[2 * t] + ls4[2 * t + 1];
    float ss8 = lss4[2 * t] + lss4[2 * t + 1];
    ls8[t] = s8; lss8[t] = ss8;
    const float inv_n = 1.f / (8.f * HW);
    const float m = s8 * inv_n;
    m8[b * 32 + t] = m;
    v8[b * 32 + t] = ss8 * inv_n - m * m;
  }
  __syncthreads();
  if (t < 16) {
    float s16  = ls8[2 * t] + ls8[2 * t + 1];
    float ss16 = lss8[2 * t] + lss8[2 * t + 1];
    const float inv_n = 1.f / (16.f * HW);
    const float m = s16 * inv_n;
    m16[b * 16 + t] = m;
    v16[b * 16 + t] = ss16 * inv_n - m * m;
  }
}

extern "C" void kernel_launch(void* const* d_in, const int* in_sizes, int n_in,
                              void* d_out, int out_size, void* d_ws, size_t ws_size,
                              hipStream_t stream) {
  const float* x = (const float*)d_in[0];
  float* out = (float*)d_out;
  float* s_ws = (float*)d_ws;          // [B*C]
  float* ss_ws = s_ws + NROW;          // [B*C]  (total 128 KB of d_ws)

  reduce_copy_kernel<<<NROW / 4, 256, 0, stream>>>(x, out, s_ws, ss_ws);
  stats_kernel<<<BB + 1, 256, 0, stream>>>(s_ws, ss_ws, out);
}